// Round 8
// baseline (178.160 us; speedup 1.0000x reference)
//
#include <hip/hip_runtime.h>
#include <hip/hip_bf16.h>
#include <math.h>

// Problem constants (fixed by the reference setup_inputs)
#define CC 256
#define PP 256
#define XSTR 296  // LDS x_off row stride in ushort (288 K + 8 pad)

// Workspace layout (float element offsets)
#define WS_SUM   0ull        // [256]
#define WS_SUMSQ 256ull      // [256]
#define WS_YU    512ull      // y bf16 [B][P][H][W] = 4194304 us = 2097152 f
#define WS_XT    2097664ull  // NHWC x bf16 [B][H][W][C] = 4194304 us
#define WS_WF    4194816ull  // main W frags [ksg72][ot16][quad4][ocin16][j8] = 589824 us
#define WS_WPMF  4489728ull  // offs/mask W frags [ksg72][ot2][quad4][ocin16][j8] = 73728 us
// end: 4526592 floats = 18.1 MB

typedef __attribute__((ext_vector_type(8))) short bf16x8;
typedef __attribute__((ext_vector_type(4))) float f32x4;

static __device__ inline unsigned short f2bf(float f) {
  unsigned int u = __float_as_uint(f);
  unsigned int r = (u + 0x7FFFu + ((u >> 16) & 1u)) >> 16;
  return (unsigned short)r;
}
static __device__ inline float bf2f(short s) {
  return __uint_as_float(((unsigned)(unsigned short)s) << 16);
}
static __device__ inline unsigned pack_bf2(float a, float b) {
  union { __hip_bfloat162 h2; unsigned u; } cv;
  cv.h2 = __float22bfloat162_rn(float2{a, b});
  return cv.u;
}

// ---------------------------------------------------------------------------
// K0: x NCHW -> NHWC bf16 transpose (blocks 0..1023) + weight fragment
// relayouts (blocks 1024..1663) + zero BN accumulators.
// ---------------------------------------------------------------------------
__global__ __launch_bounds__(256) void k_prep(const float* __restrict__ x,
                                              const float* __restrict__ w,
                                              const float* __restrict__ w_p,
                                              const float* __restrict__ w_m,
                                              float* __restrict__ ws) {
  int blk = blockIdx.x, t = threadIdx.x;
  if (blk < 1024) {
    __shared__ float sT[64][65];
    int b = blk >> 8, h = (blk >> 2) & 63, c0 = (blk & 3) * 64;
    const float* xs = x + ((size_t)(b * 256 + c0) * 64 + h) * 64;
    int cl = t >> 6, wl = t & 63;
#pragma unroll
    for (int it = 0; it < 16; ++it) {
      int c = cl + it * 4;
      sT[c][wl] = xs[(size_t)c * 4096 + wl];
    }
    __syncthreads();
    unsigned short* xt = (unsigned short*)(ws + WS_XT) +
                         ((size_t)b * 64 + h) * 16384 + c0;
    int c2 = t & 63, w2l = t >> 6;
#pragma unroll
    for (int it = 0; it < 16; ++it) {
      int w2 = w2l + it * 4;
      xt[(size_t)w2 * 256 + c2] = f2bf(sT[c2][w2]);
    }
  } else {
    int gid = (blk - 1024) * 256 + t;
    if (blk == 1024 && t < 512) ws[WS_SUM + t] = 0.f;  // SUM + SUMSQ
    unsigned short* wfb = (unsigned short*)(ws + WS_WF);
    for (int e = gid; e < 589824; e += 163840) {
      int j = e & 7, ocin = (e >> 3) & 15, quad = (e >> 7) & 3;
      int ot = (e >> 9) & 15, ksg = e >> 13;
      int kb = ksg / 9, ks = ksg - kb * 9;
      int c = kb * 32 + quad * 8 + j;
      int oc = ot * 16 + ocin;
      wfb[e] = f2bf(w[((size_t)oc * CC + c) * 9 + ks]);
    }
    unsigned short* wpmf = (unsigned short*)(ws + WS_WPMF);
    for (int e = gid; e < 73728; e += 163840) {
      int j = e & 7, ocin = (e >> 3) & 15, quad = (e >> 7) & 3;
      int ot = (e >> 9) & 1, ksg = e >> 10;
      int kb = ksg / 9, ks = ksg - kb * 9;
      int c = kb * 32 + quad * 8 + j;
      int oc = ot * 16 + ocin;
      float v = 0.f;
      if (oc < 18)      v = w_p[((size_t)oc * CC + c) * 9 + ks];
      else if (oc < 27) v = w_m[((size_t)(oc - 18) * CC + c) * 9 + ks];
      wpmf[e] = f2bf(v);
    }
  }
}

// ---------------------------------------------------------------------------
// K1 (fused): phase 1 = offset/mask 3x3 conv (im2col bf16 MFMA, result in
// LDS); phase 2 = deformable gather + bf16 MFMA + BN partials; y out bf16.
// grid = 512 (XCD-swizzled), block = 512 (8 waves), 32 px per block.
// ---------------------------------------------------------------------------
__global__ __launch_bounds__(512, 6) void k_deform(const float* __restrict__ b_p,
                                                   const float* __restrict__ b_m,
                                                   float* __restrict__ ws) {
  const unsigned short* xT = (const unsigned short*)(ws + WS_XT);
  const unsigned short* wfb = (const unsigned short*)(ws + WS_WF);
  const unsigned short* wpmf = (const unsigned short*)(ws + WS_WPMF);
  unsigned short* y = (unsigned short*)(ws + WS_YU);

  __shared__ __align__(16) unsigned short sXu0[32 * XSTR];
  __shared__ __align__(16) unsigned short sXu1[32 * XSTR];
  __shared__ float sOff[27 * 32];

  int t = threadIdx.x, blk = blockIdx.x;
  int xcd = blk & 7, ii = blk >> 3;
  int b = xcd >> 1, h = (xcd & 1) * 32 + (ii >> 1), side = ii & 1;

  int lane = t & 63, wv = __builtin_amdgcn_readfirstlane(t >> 6);
  int q = t & 3, uq = t >> 2;
  const unsigned short* xb = xT + (size_t)b * 1048576;

  // ======================= phase 1: offsets/mask =======================
  {
    int oa[3], odst[3];
#pragma unroll
    for (int r = 0; r < 3; ++r) {
      int u = r * 128 + uq;
      odst[r] = -1;
      oa[r] = -1;
      if (u < 288) {
        int j = u >> 5, px = u & 31;
        int row = h + j / 3 - 1, col = side * 32 + px + j % 3 - 1;
        odst[r] = px * XSTR + j * 32 + q * 8;
        if ((unsigned)row < 64u && (unsigned)col < 64u)
          oa[r] = (row * 64 + col) * 256 + q * 8;
      }
    }
    auto stage1 = [&](int kb, unsigned short* buf) {
      int cb = kb * 32;
#pragma unroll
      for (int r = 0; r < 3; ++r) {
        if (odst[r] >= 0) {
          bf16x8 v = {0, 0, 0, 0, 0, 0, 0, 0};
          if (oa[r] >= 0) v = *(const bf16x8*)(xb + oa[r] + cb);
          *(bf16x8*)&buf[odst[r]] = v;
        }
      }
    };

    int pxt = wv & 1, ot = (wv >> 1) & 1, kh = wv >> 2;
    f32x4 accP = {0.f, 0.f, 0.f, 0.f};
    stage1(0, sXu0);
    __syncthreads();
    for (int kb = 0; kb < 8; ++kb) {
      unsigned short* cur = (kb & 1) ? sXu1 : sXu0;
      unsigned short* nxt = (kb & 1) ? sXu0 : sXu1;
      if (kb < 7) stage1(kb + 1, nxt);
      const unsigned short* bb =
          &cur[(pxt * 16 + (lane & 15)) * XSTR + (lane >> 4) * 8];
#pragma unroll
      for (int ks = 0; ks < 9; ++ks) {
        if ((int)(ks >= 5) == kh) {
          int ksg = kb * 9 + ks;
          bf16x8 af =
              *(const bf16x8*)(wpmf + (size_t)ksg * 1024 + ot * 512 + lane * 8);
          bf16x8 bf = *(const bf16x8*)(bb + ks * 32);
          accP = __builtin_amdgcn_mfma_f32_16x16x32_bf16(af, bf, accP, 0, 0, 0);
        }
      }
      __syncthreads();
    }
    // cross-K-half reduce (sXu0 free: last MFMA read sXu1)
    float* sR = (float*)sXu0;
    if (kh == 1) {
      int base = (pxt * 2 + ot) * 256 + lane * 4;
#pragma unroll
      for (int r = 0; r < 4; ++r) sR[base + r] = accP[r];
    }
    __syncthreads();
    if (kh == 0) {
      int base = (pxt * 2 + ot) * 256 + lane * 4;
      int pxl = pxt * 16 + (lane & 15);
#pragma unroll
      for (int r = 0; r < 4; ++r) {
        int oc = ot * 16 + (lane >> 4) * 4 + r;
        if (oc < 27) {
          float v = accP[r] + sR[base + r];
          v += (oc < 18) ? b_p[oc] : b_m[oc - 18];
          if (oc >= 18) v = 1.f / (1.f + expf(-v));
          sOff[oc * 32 + pxl] = v;
        }
      }
    }
    __syncthreads();
  }

  // ======================= phase 2: deform GEMM =======================
  int ta0[3], ta1[3], ta2[3], ta3[3], tdst[3];
  float tg0[3], tg1[3], tg2[3], tg3[3];
#pragma unroll
  for (int r = 0; r < 3; ++r) {
    int u = r * 128 + uq;
    tdst[r] = -1;
    if (u < 288) {
      int k = u >> 5, px = u & 31;
      int w = side * 32 + px;
      float offx = sOff[k * 32 + px];
      float offy = sOff[(9 + k) * 32 + px];
      float mk   = sOff[(18 + k) * 32 + px];
      float pnx = (float)((k / 3 - 1) * 6);
      float pny = (float)((k % 3 - 1) * 6);
      float pxf = (float)(h + 1) + pnx + offx;
      float pyf = (float)(w + 1) + pny + offy;
      float fx = floorf(pxf), fy = floorf(pyf);
      float q0x = fminf(fmaxf(fx, 0.f), 75.f);
      float q1x = fminf(fmaxf(fx + 1.f, 0.f), 75.f);
      float q0y = fminf(fmaxf(fy, 0.f), 75.f);
      float q1y = fminf(fmaxf(fy + 1.f, 0.f), 75.f);
      float pxc = fminf(fmaxf(pxf, 0.f), 75.f);
      float pyc = fminf(fmaxf(pyf, 0.f), 75.f);
      float glt = (1.f + (q0x - pxc)) * (1.f + (q0y - pyc));
      float grb = (1.f - (q1x - pxc)) * (1.f - (q1y - pyc));
      float glb = (1.f + (q0x - pxc)) * (1.f - (q1y - pyc));
      float grt = (1.f - (q1x - pxc)) * (1.f + (q0y - pyc));
      int ix0 = (int)q0x - 6, ix1 = (int)q1x - 6;
      int iy0 = (int)q0y - 6, iy1 = (int)q1y - 6;
      bool v00 = (unsigned)ix0 < 64u && (unsigned)iy0 < 64u;
      bool v11 = (unsigned)ix1 < 64u && (unsigned)iy1 < 64u;
      bool v01 = (unsigned)ix0 < 64u && (unsigned)iy1 < 64u;
      bool v10 = (unsigned)ix1 < 64u && (unsigned)iy0 < 64u;
      ta0[r] = (v00 ? (ix0 * 64 + iy0) : 0) * 256 + q * 8;
      ta1[r] = (v11 ? (ix1 * 64 + iy1) : 0) * 256 + q * 8;
      ta2[r] = (v01 ? (ix0 * 64 + iy1) : 0) * 256 + q * 8;
      ta3[r] = (v10 ? (ix1 * 64 + iy0) : 0) * 256 + q * 8;
      tg0[r] = v00 ? glt * mk : 0.f;
      tg1[r] = v11 ? grb * mk : 0.f;
      tg2[r] = v01 ? glb * mk : 0.f;
      tg3[r] = v10 ? grt * mk : 0.f;
      tdst[r] = px * XSTR + k * 32 + q * 8;
    }
  }

  f32x4 acc[2][2];  // [oc-tile][px-tile]
#pragma unroll
  for (int i = 0; i < 2; ++i)
#pragma unroll
    for (int jj = 0; jj < 2; ++jj) acc[i][jj] = (f32x4){0.f, 0.f, 0.f, 0.f};

  auto stage2 = [&](int kb, unsigned short* buf) {
    int cb = kb * 32;
#pragma unroll
    for (int r = 0; r < 3; ++r) {
      if (tdst[r] >= 0) {
        bf16x8 t0 = *(const bf16x8*)(xb + ta0[r] + cb);
        bf16x8 t1 = *(const bf16x8*)(xb + ta1[r] + cb);
        bf16x8 t2 = *(const bf16x8*)(xb + ta2[r] + cb);
        bf16x8 t3 = *(const bf16x8*)(xb + ta3[r] + cb);
        float g0 = tg0[r], g1 = tg1[r], g2 = tg2[r], g3 = tg3[r];
        float v[8];
#pragma unroll
        for (int i = 0; i < 8; ++i) {
          float val = g0 * bf2f(t0[i]);
          val = fmaf(g1, bf2f(t1[i]), val);
          val = fmaf(g2, bf2f(t2[i]), val);
          val = fmaf(g3, bf2f(t3[i]), val);
          v[i] = val;
        }
        uint4 w4;
        w4.x = pack_bf2(v[0], v[1]);
        w4.y = pack_bf2(v[2], v[3]);
        w4.z = pack_bf2(v[4], v[5]);
        w4.w = pack_bf2(v[6], v[7]);
        *(uint4*)&buf[tdst[r]] = w4;
      }
    }
  };

  stage2(0, sXu0);
  __syncthreads();
  for (int kb = 0; kb < 8; ++kb) {
    unsigned short* cur = (kb & 1) ? sXu1 : sXu0;
    unsigned short* nxt = (kb & 1) ? sXu0 : sXu1;
    if (kb < 7) stage2(kb + 1, nxt);
    const unsigned short* bb0 = &cur[(lane & 15) * XSTR + (lane >> 4) * 8];
    const unsigned short* bb1 = bb0 + 16 * XSTR;
#pragma unroll
    for (int ks = 0; ks < 9; ++ks) {
      int ksg = kb * 9 + ks;
      const unsigned short* ap =
          wfb + (size_t)ksg * 8192 + (size_t)wv * 1024 + lane * 8;
      bf16x8 af0 = *(const bf16x8*)ap;
      bf16x8 af1 = *(const bf16x8*)(ap + 512);
      bf16x8 bf0 = *(const bf16x8*)(bb0 + ks * 32);
      bf16x8 bf1 = *(const bf16x8*)(bb1 + ks * 32);
      acc[0][0] = __builtin_amdgcn_mfma_f32_16x16x32_bf16(af0, bf0, acc[0][0], 0, 0, 0);
      acc[0][1] = __builtin_amdgcn_mfma_f32_16x16x32_bf16(af0, bf1, acc[0][1], 0, 0, 0);
      acc[1][0] = __builtin_amdgcn_mfma_f32_16x16x32_bf16(af1, bf0, acc[1][0], 0, 0, 0);
      acc[1][1] = __builtin_amdgcn_mfma_f32_16x16x32_bf16(af1, bf1, acc[1][1], 0, 0, 0);
    }
    __syncthreads();
  }

  // epilogue: bf16 y stores + per-channel partials (16-lane xor-reduce)
  float* sP = (float*)sXu0;  // [256] sum (sXu0 free: last MFMA read sXu1)
  float* sP2 = sP + 256;     // [256] sumsq
  int quad = lane >> 4, li = lane & 15;
  size_t ybase = ((size_t)b * PP) * 4096 + h * 64 + side * 32;
#pragma unroll
  for (int otl = 0; otl < 2; ++otl) {
#pragma unroll
    for (int r = 0; r < 4; ++r) {
      int oc = wv * 32 + otl * 16 + quad * 4 + r;
      float v0 = acc[otl][0][r];
      float v1 = acc[otl][1][r];
      unsigned short* yp = y + ybase + (size_t)oc * 4096 + li;
      yp[0] = f2bf(v0);
      yp[16] = f2bf(v1);
      float s = v0 + v1;
      float s2 = fmaf(v0, v0, v1 * v1);
      s += __shfl_xor(s, 1);  s2 += __shfl_xor(s2, 1);
      s += __shfl_xor(s, 2);  s2 += __shfl_xor(s2, 2);
      s += __shfl_xor(s, 4);  s2 += __shfl_xor(s2, 4);
      s += __shfl_xor(s, 8);  s2 += __shfl_xor(s2, 8);
      if (li == 0) {
        sP[oc] = s;
        sP2[oc] = s2;
      }
    }
  }
  __syncthreads();
  if (t < 256) {
    atomicAdd(&ws[WS_SUM + t], sP[t]);
    atomicAdd(&ws[WS_SUMSQ + t], sP2[t]);
  }
}

// ---------------------------------------------------------------------------
// K2: BN (stats inline from SUM/SUMSQ) + ReLU; bf16 y in, fp32 out.
// ---------------------------------------------------------------------------
__global__ __launch_bounds__(256) void k_bnrelu(const float* __restrict__ ws,
                                                const float* __restrict__ gamma,
                                                const float* __restrict__ beta,
                                                float* __restrict__ out) {
  const uint4* y8 = (const uint4*)(ws + WS_YU);
  float4* o4 = (float4*)out;
  const int n8 = 4 * PP * 512;  // 8 elements per unit
  for (int i = blockIdx.x * blockDim.x + threadIdx.x; i < n8;
       i += gridDim.x * blockDim.x) {
    int oc = (i >> 9) & 255;
    float s = ws[WS_SUM + oc], s2 = ws[WS_SUMSQ + oc];
    float mean = s * (1.f / 16384.f);
    float var = fmaf(s2, 1.f / 16384.f, -mean * mean);
    float rstd = rsqrtf(var + 1e-5f);
    float sc = gamma[oc] * rstd;
    float sh = fmaf(-mean, sc, beta[oc]);
    uint4 v = y8[i];
    float4 r0, r1;
    r0.x = fmaxf(fmaf(bf2f((short)(v.x & 0xFFFFu)), sc, sh), 0.f);
    r0.y = fmaxf(fmaf(bf2f((short)(v.x >> 16)), sc, sh), 0.f);
    r0.z = fmaxf(fmaf(bf2f((short)(v.y & 0xFFFFu)), sc, sh), 0.f);
    r0.w = fmaxf(fmaf(bf2f((short)(v.y >> 16)), sc, sh), 0.f);
    r1.x = fmaxf(fmaf(bf2f((short)(v.z & 0xFFFFu)), sc, sh), 0.f);
    r1.y = fmaxf(fmaf(bf2f((short)(v.z >> 16)), sc, sh), 0.f);
    r1.z = fmaxf(fmaf(bf2f((short)(v.w & 0xFFFFu)), sc, sh), 0.f);
    r1.w = fmaxf(fmaf(bf2f((short)(v.w >> 16)), sc, sh), 0.f);
    o4[i * 2] = r0;
    o4[i * 2 + 1] = r1;
  }
}

extern "C" void kernel_launch(void* const* d_in, const int* in_sizes, int n_in,
                              void* d_out, int out_size, void* d_ws,
                              size_t ws_size, hipStream_t stream) {
  const float* x     = (const float*)d_in[0];
  const float* w_p   = (const float*)d_in[1];
  const float* b_p   = (const float*)d_in[2];
  const float* w_m   = (const float*)d_in[3];
  const float* b_m   = (const float*)d_in[4];
  const float* w     = (const float*)d_in[5];
  const float* gamma = (const float*)d_in[6];
  const float* beta  = (const float*)d_in[7];
  float* ws  = (float*)d_ws;
  float* out = (float*)d_out;

  k_prep<<<1664, 256, 0, stream>>>(x, w, w_p, w_m, ws);
  k_deform<<<512, 512, 0, stream>>>(b_p, b_m, ws);
  k_bnrelu<<<1024, 256, 0, stream>>>(ws, gamma, beta, out);
}

// Round 9
// 153.452 us; speedup vs baseline: 1.1610x; 1.1610x over previous
//
#include <hip/hip_runtime.h>
#include <hip/hip_bf16.h>
#include <math.h>

// Problem constants (fixed by the reference setup_inputs)
#define CC 256
#define PP 256
#define XSTR 296  // LDS x_off row stride in ushort (288 K + 8 pad)

// Workspace layout (float element offsets)
#define WS_SUM   0ull        // [256]
#define WS_SUMSQ 256ull      // [256]
#define WS_YU    512ull      // y bf16 [B][P][H][W] = 4194304 us = 2097152 f
#define WS_XT    2097664ull  // NHWC x bf16 [B][H][W][C] = 4194304 us
#define WS_WF    4194816ull  // main W frags [ksg72][ot16][quad4][ocin16][j8] = 589824 us
#define WS_WPMF  4489728ull  // offs/mask W frags [ksg72][ot2][quad4][ocin16][j8] = 73728 us
// end: 4526592 floats = 18.1 MB

typedef __attribute__((ext_vector_type(8))) short bf16x8;
typedef __attribute__((ext_vector_type(4))) float f32x4;

static __device__ inline unsigned short f2bf(float f) {
  unsigned int u = __float_as_uint(f);
  unsigned int r = (u + 0x7FFFu + ((u >> 16) & 1u)) >> 16;
  return (unsigned short)r;
}
static __device__ inline float bf2f(short s) {
  return __uint_as_float(((unsigned)(unsigned short)s) << 16);
}
static __device__ inline unsigned pack_bf2(float a, float b) {
  union { __hip_bfloat162 h2; unsigned u; } cv;
  cv.h2 = __float22bfloat162_rn(float2{a, b});
  return cv.u;
}

// ---------------------------------------------------------------------------
// K0: x NCHW -> NHWC bf16 transpose (blocks 0..1023) + weight fragment
// relayouts (blocks 1024..1663) + zero BN accumulators.
// ---------------------------------------------------------------------------
__global__ __launch_bounds__(256) void k_prep(const float* __restrict__ x,
                                              const float* __restrict__ w,
                                              const float* __restrict__ w_p,
                                              const float* __restrict__ w_m,
                                              float* __restrict__ ws) {
  int blk = blockIdx.x, t = threadIdx.x;
  if (blk < 1024) {
    __shared__ float sT[64][65];
    int b = blk >> 8, h = (blk >> 2) & 63, c0 = (blk & 3) * 64;
    const float* xs = x + ((size_t)(b * 256 + c0) * 64 + h) * 64;
    int cl = t >> 6, wl = t & 63;
#pragma unroll
    for (int it = 0; it < 16; ++it) {
      int c = cl + it * 4;
      sT[c][wl] = xs[(size_t)c * 4096 + wl];
    }
    __syncthreads();
    unsigned short* xt = (unsigned short*)(ws + WS_XT) +
                         ((size_t)b * 64 + h) * 16384 + c0;
    int c2 = t & 63, w2l = t >> 6;
#pragma unroll
    for (int it = 0; it < 16; ++it) {
      int w2 = w2l + it * 4;
      xt[(size_t)w2 * 256 + c2] = f2bf(sT[c2][w2]);
    }
  } else {
    int gid = (blk - 1024) * 256 + t;
    if (blk == 1024 && t < 512) ws[WS_SUM + t] = 0.f;  // SUM + SUMSQ
    unsigned short* wfb = (unsigned short*)(ws + WS_WF);
    for (int e = gid; e < 589824; e += 163840) {
      int j = e & 7, ocin = (e >> 3) & 15, quad = (e >> 7) & 3;
      int ot = (e >> 9) & 15, ksg = e >> 13;
      int kb = ksg / 9, ks = ksg - kb * 9;
      int c = kb * 32 + quad * 8 + j;
      int oc = ot * 16 + ocin;
      wfb[e] = f2bf(w[((size_t)oc * CC + c) * 9 + ks]);
    }
    unsigned short* wpmf = (unsigned short*)(ws + WS_WPMF);
    for (int e = gid; e < 73728; e += 163840) {
      int j = e & 7, ocin = (e >> 3) & 15, quad = (e >> 7) & 3;
      int ot = (e >> 9) & 1, ksg = e >> 10;
      int kb = ksg / 9, ks = ksg - kb * 9;
      int c = kb * 32 + quad * 8 + j;
      int oc = ot * 16 + ocin;
      float v = 0.f;
      if (oc < 18)      v = w_p[((size_t)oc * CC + c) * 9 + ks];
      else if (oc < 27) v = w_m[((size_t)(oc - 18) * CC + c) * 9 + ks];
      wpmf[e] = f2bf(v);
    }
  }
}

// ---------------------------------------------------------------------------
// K1 (fused): phase 1 = offset/mask 3x3 conv (im2col bf16 MFMA, result in
// LDS); phase 2 = deformable gather + bf16 MFMA + BN partials; y out bf16.
// grid = 512 (XCD-swizzled), block = 512 (8 waves), 32 px per block.
// __launch_bounds__(512,4): 128-VGPR budget — (512,6) spilled (r8: VGPR=40,
// 39 MB scratch writes). LDS 41.5 KB caps at 3 blocks/CU regardless.
// ---------------------------------------------------------------------------
__global__ __launch_bounds__(512, 4) void k_deform(const float* __restrict__ b_p,
                                                   const float* __restrict__ b_m,
                                                   float* __restrict__ ws) {
  const unsigned short* xT = (const unsigned short*)(ws + WS_XT);
  const unsigned short* wfb = (const unsigned short*)(ws + WS_WF);
  const unsigned short* wpmf = (const unsigned short*)(ws + WS_WPMF);
  unsigned short* y = (unsigned short*)(ws + WS_YU);

  __shared__ __align__(16) unsigned short sXu0[32 * XSTR];
  __shared__ __align__(16) unsigned short sXu1[32 * XSTR];
  __shared__ float sOff[27 * 32];

  int t = threadIdx.x, blk = blockIdx.x;
  int xcd = blk & 7, ii = blk >> 3;
  int b = xcd >> 1, h = (xcd & 1) * 32 + (ii >> 1), side = ii & 1;

  int lane = t & 63, wv = __builtin_amdgcn_readfirstlane(t >> 6);
  int q = t & 3, uq = t >> 2;
  const unsigned short* xb = xT + (size_t)b * 1048576;

  // ======================= phase 1: offsets/mask =======================
  {
    int oa[3], odst[3];
#pragma unroll
    for (int r = 0; r < 3; ++r) {
      int u = r * 128 + uq;
      odst[r] = -1;
      oa[r] = -1;
      if (u < 288) {
        int j = u >> 5, px = u & 31;
        int row = h + j / 3 - 1, col = side * 32 + px + j % 3 - 1;
        odst[r] = px * XSTR + j * 32 + q * 8;
        if ((unsigned)row < 64u && (unsigned)col < 64u)
          oa[r] = (row * 64 + col) * 256 + q * 8;
      }
    }
    auto stage1 = [&](int kb, unsigned short* buf) {
      int cb = kb * 32;
#pragma unroll
      for (int r = 0; r < 3; ++r) {
        if (odst[r] >= 0) {
          bf16x8 v = {0, 0, 0, 0, 0, 0, 0, 0};
          if (oa[r] >= 0) v = *(const bf16x8*)(xb + oa[r] + cb);
          *(bf16x8*)&buf[odst[r]] = v;
        }
      }
    };

    int pxt = wv & 1, ot = (wv >> 1) & 1, kh = wv >> 2;
    f32x4 accP = {0.f, 0.f, 0.f, 0.f};
    stage1(0, sXu0);
    __syncthreads();
    for (int kb = 0; kb < 8; ++kb) {
      unsigned short* cur = (kb & 1) ? sXu1 : sXu0;
      unsigned short* nxt = (kb & 1) ? sXu0 : sXu1;
      if (kb < 7) stage1(kb + 1, nxt);
      const unsigned short* bb =
          &cur[(pxt * 16 + (lane & 15)) * XSTR + (lane >> 4) * 8];
#pragma unroll
      for (int ks = 0; ks < 9; ++ks) {
        if ((int)(ks >= 5) == kh) {
          int ksg = kb * 9 + ks;
          bf16x8 af =
              *(const bf16x8*)(wpmf + (size_t)ksg * 1024 + ot * 512 + lane * 8);
          bf16x8 bf = *(const bf16x8*)(bb + ks * 32);
          accP = __builtin_amdgcn_mfma_f32_16x16x32_bf16(af, bf, accP, 0, 0, 0);
        }
      }
      __syncthreads();
    }
    // cross-K-half reduce (sXu0 free: last MFMA read sXu1)
    float* sR = (float*)sXu0;
    if (kh == 1) {
      int base = (pxt * 2 + ot) * 256 + lane * 4;
#pragma unroll
      for (int r = 0; r < 4; ++r) sR[base + r] = accP[r];
    }
    __syncthreads();
    if (kh == 0) {
      int base = (pxt * 2 + ot) * 256 + lane * 4;
      int pxl = pxt * 16 + (lane & 15);
#pragma unroll
      for (int r = 0; r < 4; ++r) {
        int oc = ot * 16 + (lane >> 4) * 4 + r;
        if (oc < 27) {
          float v = accP[r] + sR[base + r];
          v += (oc < 18) ? b_p[oc] : b_m[oc - 18];
          if (oc >= 18) v = 1.f / (1.f + expf(-v));
          sOff[oc * 32 + pxl] = v;
        }
      }
    }
    __syncthreads();
  }

  // ======================= phase 2: deform GEMM =======================
  int ta0[3], ta1[3], ta2[3], ta3[3], tdst[3];
  float tg0[3], tg1[3], tg2[3], tg3[3];
#pragma unroll
  for (int r = 0; r < 3; ++r) {
    int u = r * 128 + uq;
    tdst[r] = -1;
    if (u < 288) {
      int k = u >> 5, px = u & 31;
      int w = side * 32 + px;
      float offx = sOff[k * 32 + px];
      float offy = sOff[(9 + k) * 32 + px];
      float mk   = sOff[(18 + k) * 32 + px];
      float pnx = (float)((k / 3 - 1) * 6);
      float pny = (float)((k % 3 - 1) * 6);
      float pxf = (float)(h + 1) + pnx + offx;
      float pyf = (float)(w + 1) + pny + offy;
      float fx = floorf(pxf), fy = floorf(pyf);
      float q0x = fminf(fmaxf(fx, 0.f), 75.f);
      float q1x = fminf(fmaxf(fx + 1.f, 0.f), 75.f);
      float q0y = fminf(fmaxf(fy, 0.f), 75.f);
      float q1y = fminf(fmaxf(fy + 1.f, 0.f), 75.f);
      float pxc = fminf(fmaxf(pxf, 0.f), 75.f);
      float pyc = fminf(fmaxf(pyf, 0.f), 75.f);
      float glt = (1.f + (q0x - pxc)) * (1.f + (q0y - pyc));
      float grb = (1.f - (q1x - pxc)) * (1.f - (q1y - pyc));
      float glb = (1.f + (q0x - pxc)) * (1.f - (q1y - pyc));
      float grt = (1.f - (q1x - pxc)) * (1.f + (q0y - pyc));
      int ix0 = (int)q0x - 6, ix1 = (int)q1x - 6;
      int iy0 = (int)q0y - 6, iy1 = (int)q1y - 6;
      bool v00 = (unsigned)ix0 < 64u && (unsigned)iy0 < 64u;
      bool v11 = (unsigned)ix1 < 64u && (unsigned)iy1 < 64u;
      bool v01 = (unsigned)ix0 < 64u && (unsigned)iy1 < 64u;
      bool v10 = (unsigned)ix1 < 64u && (unsigned)iy0 < 64u;
      ta0[r] = (v00 ? (ix0 * 64 + iy0) : 0) * 256 + q * 8;
      ta1[r] = (v11 ? (ix1 * 64 + iy1) : 0) * 256 + q * 8;
      ta2[r] = (v01 ? (ix0 * 64 + iy1) : 0) * 256 + q * 8;
      ta3[r] = (v10 ? (ix1 * 64 + iy0) : 0) * 256 + q * 8;
      tg0[r] = v00 ? glt * mk : 0.f;
      tg1[r] = v11 ? grb * mk : 0.f;
      tg2[r] = v01 ? glb * mk : 0.f;
      tg3[r] = v10 ? grt * mk : 0.f;
      tdst[r] = px * XSTR + k * 32 + q * 8;
    }
  }

  f32x4 acc[2][2];  // [oc-tile][px-tile]
#pragma unroll
  for (int i = 0; i < 2; ++i)
#pragma unroll
    for (int jj = 0; jj < 2; ++jj) acc[i][jj] = (f32x4){0.f, 0.f, 0.f, 0.f};

  auto stage2 = [&](int kb, unsigned short* buf) {
    int cb = kb * 32;
#pragma unroll
    for (int r = 0; r < 3; ++r) {
      if (tdst[r] >= 0) {
        bf16x8 t0 = *(const bf16x8*)(xb + ta0[r] + cb);
        bf16x8 t1 = *(const bf16x8*)(xb + ta1[r] + cb);
        bf16x8 t2 = *(const bf16x8*)(xb + ta2[r] + cb);
        bf16x8 t3 = *(const bf16x8*)(xb + ta3[r] + cb);
        float g0 = tg0[r], g1 = tg1[r], g2 = tg2[r], g3 = tg3[r];
        float v[8];
#pragma unroll
        for (int i = 0; i < 8; ++i) {
          float val = g0 * bf2f(t0[i]);
          val = fmaf(g1, bf2f(t1[i]), val);
          val = fmaf(g2, bf2f(t2[i]), val);
          val = fmaf(g3, bf2f(t3[i]), val);
          v[i] = val;
        }
        uint4 w4;
        w4.x = pack_bf2(v[0], v[1]);
        w4.y = pack_bf2(v[2], v[3]);
        w4.z = pack_bf2(v[4], v[5]);
        w4.w = pack_bf2(v[6], v[7]);
        *(uint4*)&buf[tdst[r]] = w4;
      }
    }
  };

  stage2(0, sXu0);
  __syncthreads();
  for (int kb = 0; kb < 8; ++kb) {
    unsigned short* cur = (kb & 1) ? sXu1 : sXu0;
    unsigned short* nxt = (kb & 1) ? sXu0 : sXu1;
    if (kb < 7) stage2(kb + 1, nxt);
    const unsigned short* bb0 = &cur[(lane & 15) * XSTR + (lane >> 4) * 8];
    const unsigned short* bb1 = bb0 + 16 * XSTR;
#pragma unroll
    for (int ks = 0; ks < 9; ++ks) {
      int ksg = kb * 9 + ks;
      const unsigned short* ap =
          wfb + (size_t)ksg * 8192 + (size_t)wv * 1024 + lane * 8;
      bf16x8 af0 = *(const bf16x8*)ap;
      bf16x8 af1 = *(const bf16x8*)(ap + 512);
      bf16x8 bf0 = *(const bf16x8*)(bb0 + ks * 32);
      bf16x8 bf1 = *(const bf16x8*)(bb1 + ks * 32);
      acc[0][0] = __builtin_amdgcn_mfma_f32_16x16x32_bf16(af0, bf0, acc[0][0], 0, 0, 0);
      acc[0][1] = __builtin_amdgcn_mfma_f32_16x16x32_bf16(af0, bf1, acc[0][1], 0, 0, 0);
      acc[1][0] = __builtin_amdgcn_mfma_f32_16x16x32_bf16(af1, bf0, acc[1][0], 0, 0, 0);
      acc[1][1] = __builtin_amdgcn_mfma_f32_16x16x32_bf16(af1, bf1, acc[1][1], 0, 0, 0);
    }
    __syncthreads();
  }

  // epilogue: bf16 y stores + per-channel partials (16-lane xor-reduce)
  float* sP = (float*)sXu0;  // [256] sum (sXu0 free: last MFMA read sXu1)
  float* sP2 = sP + 256;     // [256] sumsq
  int quad = lane >> 4, li = lane & 15;
  size_t ybase = ((size_t)b * PP) * 4096 + h * 64 + side * 32;
#pragma unroll
  for (int otl = 0; otl < 2; ++otl) {
#pragma unroll
    for (int r = 0; r < 4; ++r) {
      int oc = wv * 32 + otl * 16 + quad * 4 + r;
      float v0 = acc[otl][0][r];
      float v1 = acc[otl][1][r];
      unsigned short* yp = y + ybase + (size_t)oc * 4096 + li;
      yp[0] = f2bf(v0);
      yp[16] = f2bf(v1);
      float s = v0 + v1;
      float s2 = fmaf(v0, v0, v1 * v1);
      s += __shfl_xor(s, 1);  s2 += __shfl_xor(s2, 1);
      s += __shfl_xor(s, 2);  s2 += __shfl_xor(s2, 2);
      s += __shfl_xor(s, 4);  s2 += __shfl_xor(s2, 4);
      s += __shfl_xor(s, 8);  s2 += __shfl_xor(s2, 8);
      if (li == 0) {
        sP[oc] = s;
        sP2[oc] = s2;
      }
    }
  }
  __syncthreads();
  if (t < 256) {
    atomicAdd(&ws[WS_SUM + t], sP[t]);
    atomicAdd(&ws[WS_SUMSQ + t], sP2[t]);
  }
}

// ---------------------------------------------------------------------------
// K2: BN (stats inline from SUM/SUMSQ) + ReLU; bf16 y in, fp32 out.
// ---------------------------------------------------------------------------
__global__ __launch_bounds__(256) void k_bnrelu(const float* __restrict__ ws,
                                                const float* __restrict__ gamma,
                                                const float* __restrict__ beta,
                                                float* __restrict__ out) {
  const uint4* y8 = (const uint4*)(ws + WS_YU);
  float4* o4 = (float4*)out;
  const int n8 = 4 * PP * 512;  // 8 elements per unit
  for (int i = blockIdx.x * blockDim.x + threadIdx.x; i < n8;
       i += gridDim.x * blockDim.x) {
    int oc = (i >> 9) & 255;
    float s = ws[WS_SUM + oc], s2 = ws[WS_SUMSQ + oc];
    float mean = s * (1.f / 16384.f);
    float var = fmaf(s2, 1.f / 16384.f, -mean * mean);
    float rstd = rsqrtf(var + 1e-5f);
    float sc = gamma[oc] * rstd;
    float sh = fmaf(-mean, sc, beta[oc]);
    uint4 v = y8[i];
    float4 r0, r1;
    r0.x = fmaxf(fmaf(bf2f((short)(v.x & 0xFFFFu)), sc, sh), 0.f);
    r0.y = fmaxf(fmaf(bf2f((short)(v.x >> 16)), sc, sh), 0.f);
    r0.z = fmaxf(fmaf(bf2f((short)(v.y & 0xFFFFu)), sc, sh), 0.f);
    r0.w = fmaxf(fmaf(bf2f((short)(v.y >> 16)), sc, sh), 0.f);
    r1.x = fmaxf(fmaf(bf2f((short)(v.z & 0xFFFFu)), sc, sh), 0.f);
    r1.y = fmaxf(fmaf(bf2f((short)(v.z >> 16)), sc, sh), 0.f);
    r1.z = fmaxf(fmaf(bf2f((short)(v.w & 0xFFFFu)), sc, sh), 0.f);
    r1.w = fmaxf(fmaf(bf2f((short)(v.w >> 16)), sc, sh), 0.f);
    o4[i * 2] = r0;
    o4[i * 2 + 1] = r1;
  }
}

extern "C" void kernel_launch(void* const* d_in, const int* in_sizes, int n_in,
                              void* d_out, int out_size, void* d_ws,
                              size_t ws_size, hipStream_t stream) {
  const float* x     = (const float*)d_in[0];
  const float* w_p   = (const float*)d_in[1];
  const float* b_p   = (const float*)d_in[2];
  const float* w_m   = (const float*)d_in[3];
  const float* b_m   = (const float*)d_in[4];
  const float* w     = (const float*)d_in[5];
  const float* gamma = (const float*)d_in[6];
  const float* beta  = (const float*)d_in[7];
  float* ws  = (float*)d_ws;
  float* out = (float*)d_out;

  k_prep<<<1664, 256, 0, stream>>>(x, w, w_p, w_m, ws);
  k_deform<<<512, 512, 0, stream>>>(b_p, b_m, ws);
  k_bnrelu<<<1024, 256, 0, stream>>>(ws, gamma, beta, out);
}